// Round 8
// baseline (159.796 us; speedup 1.0000x reference)
//
#include <hip/hip_runtime.h>

#define B_ 2
#define T_ 2048
#define C_ 1024
#define H_ 16
#define D_ 64

using bf16x8 = __attribute__((ext_vector_type(8))) short;
using f32x4  = __attribute__((ext_vector_type(4))) float;

static __device__ __forceinline__ short f2bf(float f) {
  unsigned u = __builtin_bit_cast(unsigned, f);
  unsigned r = u + 0x7fffu + ((u >> 16) & 1u);
  return (short)(r >> 16);
}

#define GLD16(gp, lp) __builtin_amdgcn_global_load_lds( \
    (const __attribute__((address_space(1))) void*)(gp), \
    (__attribute__((address_space(3))) void*)(lp), 16, 0, 0)

// ---------------- cast f32 -> bf16 (vectorized) ----------------
__global__ __launch_bounds__(256) void cast_f32_bf16(const float* __restrict__ in,
                                                     short* __restrict__ out) {
  int i = blockIdx.x * blockDim.x + threadIdx.x;
  float4 v = ((const float4*)in)[i];
  short4 o;
  o.x = f2bf(v.x); o.y = f2bf(v.y); o.z = f2bf(v.z); o.w = f2bf(v.w);
  ((short4*)out)[i] = o;
}

// ---------------- transpose + cast: in [R][N] f32 -> out [N][R] bf16 ----------------
__global__ __launch_bounds__(256) void transpose_cast(const float* __restrict__ in,
                                                      short* __restrict__ out,
                                                      int R, int N) {
  __shared__ float tile[32][33];
  int bx = blockIdx.x * 32, by = blockIdx.y * 32;
  int tx = threadIdx.x, ty = threadIdx.y;
  #pragma unroll
  for (int j = 0; j < 32; j += 8)
    tile[ty + j][tx] = in[(size_t)(by + ty + j) * N + bx + tx];
  __syncthreads();
  #pragma unroll
  for (int j = 0; j < 32; j += 8)
    out[(size_t)(bx + ty + j) * R + by + tx] = f2bf(tile[tx][ty + j]);
}

// ---------------- GEMM: 128x128 tile, BK=64, global_load_lds staging ----------------
// Q prescaled by 0.125*log2(e). V-column blocks (n0>=2048) transpose their tile
// through LDS and emit Vt[b][h][d][t'] with the within-64 t-permutation
// (bit4->bit2, bits3:2->bits4:3), stored as lane-coalesced 128B rows.
__global__ __launch_bounds__(256) void gemm_qkv(const short* __restrict__ A,
                                                const short* __restrict__ Bt,
                                                const float* __restrict__ bias,
                                                short* __restrict__ Qo,
                                                short* __restrict__ Ko,
                                                short* __restrict__ Vt) {
  __shared__ short smem[128 * 132];  // staging: sA=smem[0..8191], sB=smem[8192..16383]
  short* sA = smem;
  short* sB = smem + 128 * 64;
  const int tid = threadIdx.x;
  const int w = tid >> 6, lane = tid & 63;
  const int wm = w >> 1, wn = w & 1;
  const int g = lane >> 4, r16 = lane & 15;
  const int m0 = blockIdx.x * 128, n0 = blockIdx.y * 128;
  const int krow = lane >> 3, kslot = lane & 7;

  f32x4 acc[4][4] = {};

  for (int k0 = 0; k0 < 1024; k0 += 64) {
    __syncthreads();
    #pragma unroll
    for (int p = 0; p < 4; ++p) {
      int rbase = w * 32 + p * 8;
      int row = rbase + krow;
      GLD16(&A[(size_t)(m0 + row) * 1024 + k0 + ((kslot ^ (row & 7)) * 8)], &sA[rbase * 64]);
      GLD16(&Bt[(size_t)(n0 + row) * 1024 + k0 + ((kslot ^ (row & 7)) * 8)], &sB[rbase * 64]);
    }
    __syncthreads();
    bf16x8 af[4][2], bf[4][2];
    #pragma unroll
    for (int mi = 0; mi < 4; ++mi) {
      int row = wm * 64 + mi * 16 + r16;
      #pragma unroll
      for (int c = 0; c < 2; ++c)
        af[mi][c] = *(const bf16x8*)&sA[row * 64 + (((c * 4 + g) ^ (row & 7)) * 8)];
    }
    #pragma unroll
    for (int ni = 0; ni < 4; ++ni) {
      int row = wn * 64 + ni * 16 + r16;
      #pragma unroll
      for (int c = 0; c < 2; ++c)
        bf[ni][c] = *(const bf16x8*)&sB[row * 64 + (((c * 4 + g) ^ (row & 7)) * 8)];
    }
    __builtin_amdgcn_s_setprio(1);
    #pragma unroll
    for (int mi = 0; mi < 4; ++mi)
      #pragma unroll
      for (int ni = 0; ni < 4; ++ni) {
        acc[mi][ni] = __builtin_amdgcn_mfma_f32_16x16x32_bf16(af[mi][0], bf[ni][0], acc[mi][ni], 0, 0, 0);
        acc[mi][ni] = __builtin_amdgcn_mfma_f32_16x16x32_bf16(af[mi][1], bf[ni][1], acc[mi][ni], 0, 0, 0);
      }
    __builtin_amdgcn_s_setprio(0);
  }

  if (n0 < 2048) {
    // ---- Q/K epilogue (block-uniform which) ----
    const int which = n0 >> 10;
    short* dst = (which == 0) ? Qo : Ko;
    const float sc = (which == 0) ? 0.18033688f : 1.0f;  // 0.125 * log2(e) into Q
    #pragma unroll
    for (int mi = 0; mi < 4; ++mi) {
      #pragma unroll
      for (int ni = 0; ni < 4; ++ni) {
        int n = n0 + wn * 64 + ni * 16 + r16;
        float bv = bias[n];
        int c = n & 1023;
        int hh = c >> 6, d = c & 63;
        #pragma unroll
        for (int rr = 0; rr < 4; ++rr) {
          int m = m0 + wm * 64 + mi * 16 + g * 4 + rr;
          int b = m >> 11, t = m & 2047;
          dst[(size_t)((b * H_ + hh) * T_ + t) * D_ + d] = f2bf((acc[mi][ni][rr] + bv) * sc);
        }
      }
    }
  } else {
    // ---- V epilogue: LDS transpose -> coalesced permuted Vt store ----
    __syncthreads();  // all waves done with staging reads
    #pragma unroll
    for (int mi = 0; mi < 4; ++mi) {
      #pragma unroll
      for (int ni = 0; ni < 4; ++ni) {
        int nn = wn * 64 + ni * 16 + r16;
        float bv = bias[n0 + nn];
        #pragma unroll
        for (int rr = 0; rr < 4; ++rr) {
          int tm = wm * 64 + mi * 16 + g * 4 + rr;
          smem[tm * 132 + nn] = f2bf(acc[mi][ni][rr] + bv);
        }
      }
    }
    __syncthreads();
    // inverse key permutation: in2=out3, in3=out4, in4=out2
    const int tinv = (lane & ~0x1C) | ((lane & 0x18) >> 1) | ((lane & 4) << 2);
    const int b2 = m0 >> 11, t0l = m0 & 2047;
    const int head0 = b2 * H_ + ((n0 - 2048) >> 6);
    #pragma unroll 8
    for (int i = 0; i < 64; ++i) {
      int half = i >> 5, nnl = i & 31;
      int nn = w * 32 + nnl;
      int d = nn & 63, hh2 = nn >> 6;
      short val = smem[(half * 64 + tinv) * 132 + nn];
      Vt[((size_t)(head0 + hh2) * D_ + d) * T_ + t0l + half * 64 + lane] = val;
    }
  }
}

__global__ __launch_bounds__(256) void gemm_out(const short* __restrict__ A,
                                                const short* __restrict__ Bt,
                                                const float* __restrict__ bias,
                                                float* __restrict__ Out) {
  __shared__ short sA[128 * 64];
  __shared__ short sB[128 * 64];
  const int tid = threadIdx.x;
  const int w = tid >> 6, lane = tid & 63;
  const int wm = w >> 1, wn = w & 1;
  const int g = lane >> 4, r16 = lane & 15;
  const int m0 = blockIdx.x * 128, n0 = blockIdx.y * 128;
  const int krow = lane >> 3, kslot = lane & 7;

  f32x4 acc[4][4] = {};

  for (int k0 = 0; k0 < 1024; k0 += 64) {
    __syncthreads();
    #pragma unroll
    for (int p = 0; p < 4; ++p) {
      int rbase = w * 32 + p * 8;
      int row = rbase + krow;
      GLD16(&A[(size_t)(m0 + row) * 1024 + k0 + ((kslot ^ (row & 7)) * 8)], &sA[rbase * 64]);
      GLD16(&Bt[(size_t)(n0 + row) * 1024 + k0 + ((kslot ^ (row & 7)) * 8)], &sB[rbase * 64]);
    }
    __syncthreads();
    bf16x8 af[4][2], bf[4][2];
    #pragma unroll
    for (int mi = 0; mi < 4; ++mi) {
      int row = wm * 64 + mi * 16 + r16;
      #pragma unroll
      for (int c = 0; c < 2; ++c)
        af[mi][c] = *(const bf16x8*)&sA[row * 64 + (((c * 4 + g) ^ (row & 7)) * 8)];
    }
    #pragma unroll
    for (int ni = 0; ni < 4; ++ni) {
      int row = wn * 64 + ni * 16 + r16;
      #pragma unroll
      for (int c = 0; c < 2; ++c)
        bf[ni][c] = *(const bf16x8*)&sB[row * 64 + (((c * 4 + g) ^ (row & 7)) * 8)];
    }
    __builtin_amdgcn_s_setprio(1);
    #pragma unroll
    for (int mi = 0; mi < 4; ++mi)
      #pragma unroll
      for (int ni = 0; ni < 4; ++ni) {
        acc[mi][ni] = __builtin_amdgcn_mfma_f32_16x16x32_bf16(af[mi][0], bf[ni][0], acc[mi][ni], 0, 0, 0);
        acc[mi][ni] = __builtin_amdgcn_mfma_f32_16x16x32_bf16(af[mi][1], bf[ni][1], acc[mi][ni], 0, 0, 0);
      }
    __builtin_amdgcn_s_setprio(0);
  }

  #pragma unroll
  for (int mi = 0; mi < 4; ++mi) {
    #pragma unroll
    for (int ni = 0; ni < 4; ++ni) {
      int n = n0 + wn * 64 + ni * 16 + r16;
      float bv = bias[n];
      #pragma unroll
      for (int rr = 0; rr < 4; ++rr) {
        int m = m0 + wm * 64 + mi * 16 + g * 4 + rr;
        Out[(size_t)m * 1024 + n] = acc[mi][ni][rr] + bv;
      }
    }
  }
}

// ---------------- flash attention: K in LDS (shared, dbuf), V direct from Vt ----------------
// grid (bh=32, 32); qi = 31 - blockIdx.y (LPT). 4 waves x 16 q-rows, KVBLK=64.
// Swapped mfma(K,Q) softmax fully in-register; packed P feeds PV directly.
// vb B-frags load straight from permuted Vt (global, issued early -> latency hidden).
__global__ __launch_bounds__(256, 4) void attn_fwd(const short* __restrict__ Q,
                                                   const short* __restrict__ K,
                                                   const short* __restrict__ Vt,
                                                   short* __restrict__ O) {
  __shared__ short sK[2][64 * 64];   // [key][d], chunk c holds d-chunk c^(key&7)

  const int tid = threadIdx.x;
  const int w = tid >> 6, lane = tid & 63;
  const int g = lane >> 4, r16 = lane & 15;
  const int bh = blockIdx.x;
  const int b = bh >> 4, hh = bh & 15;
  const int qi = 31 - (int)blockIdx.y;  // LPT: heavy first
  const int q0 = qi * 64;

  const short* Qh = Q + (size_t)bh * T_ * D_;
  const short* Kh = K + (size_t)bh * T_ * D_;
  const short* Vh = Vt + (size_t)bh * D_ * T_;   // [d][t'] permuted

  const int krow_in_wave = lane >> 3;
  const int kslot = lane & 7;

  const int qrow_a = q0 + w * 16 + r16;
  bf16x8 qf[2];
  qf[0] = *(const bf16x8*)&Qh[(size_t)qrow_a * 64 + g * 8];
  qf[1] = *(const bf16x8*)&Qh[(size_t)qrow_a * 64 + 32 + g * 8];

  f32x4 o[4] = {};
  float m_ = -1e30f, l_ = 0.f;

  const int nkt = qi + 1;

  // ---- prologue: stage K(0) ----
  #pragma unroll
  for (int p = 0; p < 2; ++p) {
    int row = w * 16 + p * 8 + krow_in_wave;
    GLD16(&Kh[(size_t)row * 64 + ((kslot ^ (row & 7)) * 8)], &sK[0][(w * 16 + p * 8) * 64]);
  }
  __syncthreads();

  for (int kt = 0; kt < nkt; ++kt) {
    const int cur = kt & 1;
    const int k0 = kt * 64;

    // ---- issue V(kt) B-frag loads (consumed after softmax; latency hidden) ----
    bf16x8 vb[4][2];
    #pragma unroll
    for (int nt = 0; nt < 4; ++nt) {
      const size_t voff = (size_t)(nt * 16 + r16) * T_ + k0;
      vb[nt][0] = *(const bf16x8*)&Vh[voff + g * 8];
      vb[nt][1] = *(const bf16x8*)&Vh[voff + 32 + g * 8];
    }
    // ---- prefetch K(kt+1) into other buffer ----
    if (kt + 1 < nkt) {
      const int k1 = k0 + 64;
      #pragma unroll
      for (int p = 0; p < 2; ++p) {
        int row = w * 16 + p * 8 + krow_in_wave;
        GLD16(&Kh[(size_t)(k1 + row) * 64 + ((kslot ^ (row & 7)) * 8)],
              &sK[cur ^ 1][(w * 16 + p * 8) * 64]);
      }
    }

    // ---- S^T = K Q^T : lane holds S[key = nt*16+4g+rr][q = r16] ----
    f32x4 s[4] = {};
    __builtin_amdgcn_s_setprio(1);
    #pragma unroll
    for (int nt = 0; nt < 4; ++nt) {
      const int row = nt * 16 + r16;
      const int sw8 = r16 & 7;
      bf16x8 kf0 = *(const bf16x8*)&sK[cur][row * 64 + ((g ^ sw8) * 8)];
      bf16x8 kf1 = *(const bf16x8*)&sK[cur][row * 64 + (((4 + g) ^ sw8) * 8)];
      s[nt] = __builtin_amdgcn_mfma_f32_16x16x32_bf16(kf0, qf[0], s[nt], 0, 0, 0);
      s[nt] = __builtin_amdgcn_mfma_f32_16x16x32_bf16(kf1, qf[1], s[nt], 0, 0, 0);
    }
    __builtin_amdgcn_s_setprio(0);

    // ---- online softmax (log2 domain; Q prescaled) ----
    if (kt == nkt - 1) {  // diagonal tile
      const int qrow = w * 16 + r16;
      #pragma unroll
      for (int nt = 0; nt < 4; ++nt)
        #pragma unroll
        for (int rr = 0; rr < 4; ++rr)
          if (nt * 16 + 4 * g + rr > qrow) s[nt][rr] = -1e30f;
    }
    float pmax = s[0][0];
    #pragma unroll
    for (int nt = 0; nt < 4; ++nt)
      #pragma unroll
      for (int rr = 0; rr < 4; ++rr)
        pmax = fmaxf(pmax, s[nt][rr]);
    pmax = fmaxf(pmax, __shfl_xor(pmax, 16));
    pmax = fmaxf(pmax, __shfl_xor(pmax, 32));
    if (!__all(pmax - m_ <= 8.0f)) {  // defer-max (T13)
      float mn = fmaxf(m_, pmax);
      float al = __builtin_amdgcn_exp2f(m_ - mn);
      m_ = mn;
      l_ *= al;
      float av[4];
      #pragma unroll
      for (int rr = 0; rr < 4; ++rr) av[rr] = __shfl(al, 4 * g + rr, 16);
      #pragma unroll
      for (int nt = 0; nt < 4; ++nt)
        #pragma unroll
        for (int rr = 0; rr < 4; ++rr) o[nt][rr] *= av[rr];
    }
    float rs = 0.f;
    #pragma unroll
    for (int nt = 0; nt < 4; ++nt)
      #pragma unroll
      for (int rr = 0; rr < 4; ++rr) {
        float p = __builtin_amdgcn_exp2f(s[nt][rr] - m_);
        s[nt][rr] = p;
        rs += p;
      }
    rs += __shfl_xor(rs, 16);
    rs += __shfl_xor(rs, 32);
    l_ += rs;
    int pk[8];
    #pragma unroll
    for (int nt = 0; nt < 4; ++nt)
      #pragma unroll
      for (int h = 0; h < 2; ++h)
        asm("v_cvt_pk_bf16_f32 %0, %1, %2"
            : "=v"(pk[nt * 2 + h])
            : "v"(s[nt][2 * h]), "v"(s[nt][2 * h + 1]));

    // ---- O += P @ V : packed P is the A-fragment directly ----
    bf16x8 pa[2];
    {
      int4 t0; t0.x = pk[0]; t0.y = pk[1]; t0.z = pk[2]; t0.w = pk[3];
      int4 t1; t1.x = pk[4]; t1.y = pk[5]; t1.z = pk[6]; t1.w = pk[7];
      pa[0] = __builtin_bit_cast(bf16x8, t0);
      pa[1] = __builtin_bit_cast(bf16x8, t1);
    }
    __builtin_amdgcn_s_setprio(1);
    #pragma unroll
    for (int nt = 0; nt < 4; ++nt) {
      o[nt] = __builtin_amdgcn_mfma_f32_16x16x32_bf16(pa[0], vb[nt][0], o[nt], 0, 0, 0);
      o[nt] = __builtin_amdgcn_mfma_f32_16x16x32_bf16(pa[1], vb[nt][1], o[nt], 0, 0, 0);
    }
    __builtin_amdgcn_s_setprio(0);

    __syncthreads();  // K(kt+1) staged; sK[cur] free for next prefetch
  }

  // ---- epilogue: O /= l ----
  float lv[4];
  #pragma unroll
  for (int rr = 0; rr < 4; ++rr) lv[rr] = __shfl(l_, 4 * g + rr, 16);
  #pragma unroll
  for (int nt = 0; nt < 4; ++nt) {
    int d = nt * 16 + r16;
    #pragma unroll
    for (int rr = 0; rr < 4; ++rr) {
      int t = q0 + w * 16 + 4 * g + rr;
      O[(size_t)(b * T_ + t) * C_ + hh * 64 + d] = f2bf(o[nt][rr] / lv[rr]);
    }
  }
}

extern "C" void kernel_launch(void* const* d_in, const int* in_sizes, int n_in,
                              void* d_out, int out_size, void* d_ws, size_t ws_size,
                              hipStream_t stream) {
  const float* x     = (const float*)d_in[0];
  const float* w_qkv = (const float*)d_in[1];
  const float* b_qkv = (const float*)d_in[2];
  const float* w_out = (const float*)d_in[3];
  const float* b_out = (const float*)d_in[4];
  float* out = (float*)d_out;

  char* ws = (char*)d_ws;
  if (ws_size < (size_t)(40u << 20)) return;

  short* xb     = (short*)(ws);                        // 8 MiB  [4096][1024] bf16
  short* wqkvT  = (short*)(ws + ((size_t)8u << 20));   // 6 MiB  [3072][1024] bf16
  short* woutT  = (short*)(ws + ((size_t)14u << 20));  // 2 MiB  [1024][1024] bf16
  short* Qb     = (short*)(ws + ((size_t)16u << 20));  // 8 MiB  [B][H][T][D] (prescaled)
  short* Kb     = (short*)(ws + ((size_t)24u << 20));  // 8 MiB  [B][H][T][D]
  short* Vtb    = (short*)(ws + ((size_t)32u << 20));  // 8 MiB  [B][H][D][T'] permuted
  short* attn_o = xb;  // xb dead after gemm_qkv

  cast_f32_bf16<<<4096, 256, 0, stream>>>(x, xb);
  transpose_cast<<<dim3(96, 32), dim3(32, 8), 0, stream>>>(w_qkv, wqkvT, 1024, 3072);
  transpose_cast<<<dim3(32, 32), dim3(32, 8), 0, stream>>>(w_out, woutT, 1024, 1024);
  gemm_qkv<<<dim3(32, 24), 256, 0, stream>>>(xb, wqkvT, b_qkv, Qb, Kb, Vtb);
  attn_fwd<<<dim3(32, 32), 256, 0, stream>>>(Qb, Kb, Vtb, attn_o);
  gemm_out<<<dim3(32, 8), 256, 0, stream>>>(attn_o, woutT, b_out, out);
}

// Round 9
// 119.339 us; speedup vs baseline: 1.3390x; 1.3390x over previous
//
#include <hip/hip_runtime.h>

#define B_ 2
#define T_ 2048
#define C_ 1024
#define H_ 16
#define D_ 64

using bf16x8 = __attribute__((ext_vector_type(8))) short;
using f32x4  = __attribute__((ext_vector_type(4))) float;

static __device__ __forceinline__ short f2bf(float f) {
  unsigned u = __builtin_bit_cast(unsigned, f);
  unsigned r = u + 0x7fffu + ((u >> 16) & 1u);
  return (short)(r >> 16);
}

#define GLD16(gp, lp) __builtin_amdgcn_global_load_lds( \
    (const __attribute__((address_space(1))) void*)(gp), \
    (__attribute__((address_space(3))) void*)(lp), 16, 0, 0)

// ---------------- cast f32 -> bf16 (vectorized) ----------------
__global__ __launch_bounds__(256) void cast_f32_bf16(const float* __restrict__ in,
                                                     short* __restrict__ out) {
  int i = blockIdx.x * blockDim.x + threadIdx.x;
  float4 v = ((const float4*)in)[i];
  short4 o;
  o.x = f2bf(v.x); o.y = f2bf(v.y); o.z = f2bf(v.z); o.w = f2bf(v.w);
  ((short4*)out)[i] = o;
}

// ---------------- transpose + cast: in [R][N] f32 -> out [N][R] bf16 ----------------
__global__ __launch_bounds__(256) void transpose_cast(const float* __restrict__ in,
                                                      short* __restrict__ out,
                                                      int R, int N) {
  __shared__ float tile[32][33];
  int bx = blockIdx.x * 32, by = blockIdx.y * 32;
  int tx = threadIdx.x, ty = threadIdx.y;
  #pragma unroll
  for (int j = 0; j < 32; j += 8)
    tile[ty + j][tx] = in[(size_t)(by + ty + j) * N + bx + tx];
  __syncthreads();
  #pragma unroll
  for (int j = 0; j < 32; j += 8)
    out[(size_t)(bx + ty + j) * R + by + tx] = f2bf(tile[tx][ty + j]);
}

// ---------------- GEMM: 128x128 tile, BK=64, global_load_lds staging ----------------
// Q prescaled by 0.125*log2(e) so attention uses exp2 directly.
__global__ __launch_bounds__(256) void gemm_qkv(const short* __restrict__ A,
                                                const short* __restrict__ Bt,
                                                const float* __restrict__ bias,
                                                short* __restrict__ Qo,
                                                short* __restrict__ Ko,
                                                short* __restrict__ Vo) {
  __shared__ short sA[128 * 64];
  __shared__ short sB[128 * 64];
  const int tid = threadIdx.x;
  const int w = tid >> 6, lane = tid & 63;
  const int wm = w >> 1, wn = w & 1;
  const int g = lane >> 4, r16 = lane & 15;
  const int m0 = blockIdx.x * 128, n0 = blockIdx.y * 128;
  const int krow = lane >> 3, kslot = lane & 7;

  f32x4 acc[4][4] = {};

  for (int k0 = 0; k0 < 1024; k0 += 64) {
    __syncthreads();
    #pragma unroll
    for (int p = 0; p < 4; ++p) {
      int rbase = w * 32 + p * 8;
      int row = rbase + krow;
      GLD16(&A[(size_t)(m0 + row) * 1024 + k0 + ((kslot ^ (row & 7)) * 8)], &sA[rbase * 64]);
      GLD16(&Bt[(size_t)(n0 + row) * 1024 + k0 + ((kslot ^ (row & 7)) * 8)], &sB[rbase * 64]);
    }
    __syncthreads();
    bf16x8 af[4][2], bf[4][2];
    #pragma unroll
    for (int mi = 0; mi < 4; ++mi) {
      int row = wm * 64 + mi * 16 + r16;
      #pragma unroll
      for (int c = 0; c < 2; ++c)
        af[mi][c] = *(const bf16x8*)&sA[row * 64 + (((c * 4 + g) ^ (row & 7)) * 8)];
    }
    #pragma unroll
    for (int ni = 0; ni < 4; ++ni) {
      int row = wn * 64 + ni * 16 + r16;
      #pragma unroll
      for (int c = 0; c < 2; ++c)
        bf[ni][c] = *(const bf16x8*)&sB[row * 64 + (((c * 4 + g) ^ (row & 7)) * 8)];
    }
    __builtin_amdgcn_s_setprio(1);
    #pragma unroll
    for (int mi = 0; mi < 4; ++mi)
      #pragma unroll
      for (int ni = 0; ni < 4; ++ni) {
        acc[mi][ni] = __builtin_amdgcn_mfma_f32_16x16x32_bf16(af[mi][0], bf[ni][0], acc[mi][ni], 0, 0, 0);
        acc[mi][ni] = __builtin_amdgcn_mfma_f32_16x16x32_bf16(af[mi][1], bf[ni][1], acc[mi][ni], 0, 0, 0);
      }
    __builtin_amdgcn_s_setprio(0);
  }

  #pragma unroll
  for (int mi = 0; mi < 4; ++mi) {
    #pragma unroll
    for (int ni = 0; ni < 4; ++ni) {
      int n = n0 + wn * 64 + ni * 16 + r16;
      float bv = bias[n];
      int which = n >> 10;
      int c = n & 1023;
      int hh = c >> 6, d = c & 63;
      short* dst = (which == 0) ? Qo : ((which == 1) ? Ko : Vo);
      float sc = (which == 0) ? 0.18033688f : 1.0f;  // 0.125 * log2(e) folded into Q
      #pragma unroll
      for (int rr = 0; rr < 4; ++rr) {
        int m = m0 + wm * 64 + mi * 16 + g * 4 + rr;
        int b = m >> 11, t = m & 2047;
        dst[(size_t)((b * H_ + hh) * T_ + t) * D_ + d] = f2bf((acc[mi][ni][rr] + bv) * sc);
      }
    }
  }
}

__global__ __launch_bounds__(256) void gemm_out(const short* __restrict__ A,
                                                const short* __restrict__ Bt,
                                                const float* __restrict__ bias,
                                                float* __restrict__ Out) {
  __shared__ short sA[128 * 64];
  __shared__ short sB[128 * 64];
  const int tid = threadIdx.x;
  const int w = tid >> 6, lane = tid & 63;
  const int wm = w >> 1, wn = w & 1;
  const int g = lane >> 4, r16 = lane & 15;
  const int m0 = blockIdx.x * 128, n0 = blockIdx.y * 128;
  const int krow = lane >> 3, kslot = lane & 7;

  f32x4 acc[4][4] = {};

  for (int k0 = 0; k0 < 1024; k0 += 64) {
    __syncthreads();
    #pragma unroll
    for (int p = 0; p < 4; ++p) {
      int rbase = w * 32 + p * 8;
      int row = rbase + krow;
      GLD16(&A[(size_t)(m0 + row) * 1024 + k0 + ((kslot ^ (row & 7)) * 8)], &sA[rbase * 64]);
      GLD16(&Bt[(size_t)(n0 + row) * 1024 + k0 + ((kslot ^ (row & 7)) * 8)], &sB[rbase * 64]);
    }
    __syncthreads();
    bf16x8 af[4][2], bf[4][2];
    #pragma unroll
    for (int mi = 0; mi < 4; ++mi) {
      int row = wm * 64 + mi * 16 + r16;
      #pragma unroll
      for (int c = 0; c < 2; ++c)
        af[mi][c] = *(const bf16x8*)&sA[row * 64 + (((c * 4 + g) ^ (row & 7)) * 8)];
    }
    #pragma unroll
    for (int ni = 0; ni < 4; ++ni) {
      int row = wn * 64 + ni * 16 + r16;
      #pragma unroll
      for (int c = 0; c < 2; ++c)
        bf[ni][c] = *(const bf16x8*)&sB[row * 64 + (((c * 4 + g) ^ (row & 7)) * 8)];
    }
    __builtin_amdgcn_s_setprio(1);
    #pragma unroll
    for (int mi = 0; mi < 4; ++mi)
      #pragma unroll
      for (int ni = 0; ni < 4; ++ni) {
        acc[mi][ni] = __builtin_amdgcn_mfma_f32_16x16x32_bf16(af[mi][0], bf[ni][0], acc[mi][ni], 0, 0, 0);
        acc[mi][ni] = __builtin_amdgcn_mfma_f32_16x16x32_bf16(af[mi][1], bf[ni][1], acc[mi][ni], 0, 0, 0);
      }
    __builtin_amdgcn_s_setprio(0);
  }

  #pragma unroll
  for (int mi = 0; mi < 4; ++mi) {
    #pragma unroll
    for (int ni = 0; ni < 4; ++ni) {
      int n = n0 + wn * 64 + ni * 16 + r16;
      float bv = bias[n];
      #pragma unroll
      for (int rr = 0; rr < 4; ++rr) {
        int m = m0 + wm * 64 + mi * 16 + g * 4 + rr;
        Out[(size_t)m * 1024 + n] = acc[mi][ni][rr] + bv;
      }
    }
  }
}

// ---------------- flash attention: R4 skeleton + shuffle-free softmax common path -----------
// grid (bh=32, 32); qi = 31 - blockIdx.y (LPT). 4 waves x 16 q-rows, KVBLK=64, dbuf K+V LDS.
// Swapped mfma(K,Q); per-lane partial l (reduced once in epilogue); defer-max gate is a
// per-lane check (no shuffles) -> zero cross-lane ops in the steady-state iteration.
__global__ __launch_bounds__(256, 4) void attn_fwd(const short* __restrict__ Q,
                                                   const short* __restrict__ K,
                                                   const short* __restrict__ V,
                                                   short* __restrict__ O) {
  __shared__ short sK[2][64 * 64];   // [key][d], chunk c holds d-chunk c^(key&7)
  __shared__ short vT[2][64 * 64];   // [d][slot], slot = pi(key); chunk c' holds c'^(d&7)

  const int tid = threadIdx.x;
  const int w = tid >> 6, lane = tid & 63;
  const int g = lane >> 4, r16 = lane & 15;
  const int bh = blockIdx.x;
  const int b = bh >> 4, hh = bh & 15;
  const int qi = 31 - (int)blockIdx.y;  // LPT: heavy first
  const int q0 = qi * 64;

  const short* Qh = Q + (size_t)bh * T_ * D_;
  const short* Kh = K + (size_t)bh * T_ * D_;
  const short* Vh = V + (size_t)bh * T_ * D_;

  const int krow_in_wave = lane >> 3;
  const int kslot = lane & 7;
  // V slot permutation: slot = 32a + 8c + 4b + 2d + e for key = 32a+16b+4c+2d+e
  const int kp = tid & 31;
  const int vd0 = (tid >> 5) * 8;
  const int vchunk = (kp >> 4) * 4 + ((kp & 7) >> 1);
  const int velem  = ((kp >> 3) & 1) * 4 + 2 * (kp & 1);

  const int qrow_a = q0 + w * 16 + r16;
  bf16x8 qf[2];
  qf[0] = *(const bf16x8*)&Qh[(size_t)qrow_a * 64 + g * 8];
  qf[1] = *(const bf16x8*)&Qh[(size_t)qrow_a * 64 + 32 + g * 8];

  f32x4 o[4] = {};
  float m_ = -1e30f, l_ = 0.f;   // l_ is a PER-LANE partial (scale 2^-m_)

  const int nkt = qi + 1;

  // ---- prologue: stage K(0), V(0) ----
  #pragma unroll
  for (int p = 0; p < 2; ++p) {
    int row = w * 16 + p * 8 + krow_in_wave;
    GLD16(&Kh[(size_t)row * 64 + ((kslot ^ (row & 7)) * 8)], &sK[0][(w * 16 + p * 8) * 64]);
  }
  {
    int4 v0 = *(const int4*)&Vh[(size_t)(2 * kp) * 64 + vd0];
    int4 v1 = *(const int4*)&Vh[(size_t)(2 * kp + 1) * 64 + vd0];
    const short* a0 = (const short*)&v0;
    const short* a1 = (const short*)&v1;
    #pragma unroll
    for (int j = 0; j < 8; ++j) {
      int d = vd0 + j;  // d&7 == j
      int val = ((int)(unsigned short)a0[j]) | (((int)(unsigned short)a1[j]) << 16);
      *(int*)&vT[0][d * 64 + ((vchunk ^ j) * 8) + velem] = val;
    }
  }
  __syncthreads();

  for (int kt = 0; kt < nkt; ++kt) {
    const int cur = kt & 1, nxt = cur ^ 1;
    const int k0 = kt * 64;
    const bool pf = (kt + 1 < nkt);

    // ---- issue next-tile staging early (T14) ----
    int4 vn0, vn1;
    if (pf) {
      const int k1 = k0 + 64;
      #pragma unroll
      for (int p = 0; p < 2; ++p) {
        int row = w * 16 + p * 8 + krow_in_wave;
        GLD16(&Kh[(size_t)(k1 + row) * 64 + ((kslot ^ (row & 7)) * 8)],
              &sK[nxt][(w * 16 + p * 8) * 64]);
      }
      vn0 = *(const int4*)&Vh[(size_t)(k1 + 2 * kp) * 64 + vd0];
      vn1 = *(const int4*)&Vh[(size_t)(k1 + 2 * kp + 1) * 64 + vd0];
    }

    // ---- S^T = K Q^T : lane holds S[key = nt*16+4g+rr][q = r16] ----
    f32x4 s[4] = {};
    __builtin_amdgcn_s_setprio(1);
    #pragma unroll
    for (int nt = 0; nt < 4; ++nt) {
      const int row = nt * 16 + r16;
      const int sw8 = r16 & 7;
      bf16x8 kf0 = *(const bf16x8*)&sK[cur][row * 64 + ((g ^ sw8) * 8)];
      bf16x8 kf1 = *(const bf16x8*)&sK[cur][row * 64 + (((4 + g) ^ sw8) * 8)];
      s[nt] = __builtin_amdgcn_mfma_f32_16x16x32_bf16(kf0, qf[0], s[nt], 0, 0, 0);
      s[nt] = __builtin_amdgcn_mfma_f32_16x16x32_bf16(kf1, qf[1], s[nt], 0, 0, 0);
    }
    __builtin_amdgcn_s_setprio(0);

    // ---- online softmax: zero cross-lane ops in the common path ----
    if (kt == nkt - 1) {  // diagonal tile
      const int qrow = w * 16 + r16;
      #pragma unroll
      for (int nt = 0; nt < 4; ++nt)
        #pragma unroll
        for (int rr = 0; rr < 4; ++rr)
          if (nt * 16 + 4 * g + rr > qrow) s[nt][rr] = -1e30f;
    }
    float pmax = s[0][0];
    #pragma unroll
    for (int nt = 0; nt < 4; ++nt)
      #pragma unroll
      for (int rr = 0; rr < 4; ++rr)
        pmax = fmaxf(pmax, s[nt][rr]);
    // defer-max gate on PER-LANE max (no reduce needed to check)
    if (!__all(pmax - m_ <= 8.0f)) {
      float rmax = fmaxf(pmax, __shfl_xor(pmax, 16));
      rmax = fmaxf(rmax, __shfl_xor(rmax, 32));
      float mn = fmaxf(m_, rmax);
      float al = __builtin_amdgcn_exp2f(m_ - mn);
      m_ = mn;
      l_ *= al;
      float av[4];
      #pragma unroll
      for (int rr = 0; rr < 4; ++rr) av[rr] = __shfl(al, 4 * g + rr, 16);
      #pragma unroll
      for (int nt = 0; nt < 4; ++nt)
        #pragma unroll
        for (int rr = 0; rr < 4; ++rr) o[nt][rr] *= av[rr];
    }
    float rs = 0.f;
    #pragma unroll
    for (int nt = 0; nt < 4; ++nt)
      #pragma unroll
      for (int rr = 0; rr < 4; ++rr) {
        float p = __builtin_amdgcn_exp2f(s[nt][rr] - m_);
        s[nt][rr] = p;
        rs += p;
      }
    l_ += rs;  // per-lane partial; cross-lane reduce deferred to epilogue
    int pk[8];
    #pragma unroll
    for (int nt = 0; nt < 4; ++nt)
      #pragma unroll
      for (int h = 0; h < 2; ++h)
        asm("v_cvt_pk_bf16_f32 %0, %1, %2"
            : "=v"(pk[nt * 2 + h])
            : "v"(s[nt][2 * h]), "v"(s[nt][2 * h + 1]));

    // ---- O += P @ V : packed P is the A-fragment directly ----
    bf16x8 pa[2];
    {
      int4 t0; t0.x = pk[0]; t0.y = pk[1]; t0.z = pk[2]; t0.w = pk[3];
      int4 t1; t1.x = pk[4]; t1.y = pk[5]; t1.z = pk[6]; t1.w = pk[7];
      pa[0] = __builtin_bit_cast(bf16x8, t0);
      pa[1] = __builtin_bit_cast(bf16x8, t1);
    }
    __builtin_amdgcn_s_setprio(1);
    #pragma unroll
    for (int nt = 0; nt < 4; ++nt) {
      const int d = nt * 16 + r16;
      bf16x8 vb0 = *(const bf16x8*)&vT[cur][d * 64 + ((g ^ (d & 7)) * 8)];
      bf16x8 vb1 = *(const bf16x8*)&vT[cur][d * 64 + (((4 + g) ^ (d & 7)) * 8)];
      o[nt] = __builtin_amdgcn_mfma_f32_16x16x32_bf16(pa[0], vb0, o[nt], 0, 0, 0);
      o[nt] = __builtin_amdgcn_mfma_f32_16x16x32_bf16(pa[1], vb1, o[nt], 0, 0, 0);
    }
    __builtin_amdgcn_s_setprio(0);

    // ---- late stage-write of V(kt+1) ----
    if (pf) {
      const short* a0 = (const short*)&vn0;
      const short* a1 = (const short*)&vn1;
      #pragma unroll
      for (int j = 0; j < 8; ++j) {
        int d = vd0 + j;
        int val = ((int)(unsigned short)a0[j]) | (((int)(unsigned short)a1[j]) << 16);
        *(int*)&vT[nxt][d * 64 + ((vchunk ^ j) * 8) + velem] = val;
      }
    }
    __syncthreads();
  }

  // ---- epilogue: reduce per-lane l partials once, then O /= l ----
  float lt = l_ + __shfl_xor(l_, 16);
  lt += __shfl_xor(lt, 32);
  float lv[4];
  #pragma unroll
  for (int rr = 0; rr < 4; ++rr) lv[rr] = __shfl(lt, 4 * g + rr, 16);
  #pragma unroll
  for (int nt = 0; nt < 4; ++nt) {
    int d = nt * 16 + r16;
    #pragma unroll
    for (int rr = 0; rr < 4; ++rr) {
      int t = q0 + w * 16 + 4 * g + rr;
      O[(size_t)(b * T_ + t) * C_ + hh * 64 + d] = f2bf(o[nt][rr] / lv[rr]);
    }
  }
}

extern "C" void kernel_launch(void* const* d_in, const int* in_sizes, int n_in,
                              void* d_out, int out_size, void* d_ws, size_t ws_size,
                              hipStream_t stream) {
  const float* x     = (const float*)d_in[0];
  const float* w_qkv = (const float*)d_in[1];
  const float* b_qkv = (const float*)d_in[2];
  const float* w_out = (const float*)d_in[3];
  const float* b_out = (const float*)d_in[4];
  float* out = (float*)d_out;

  char* ws = (char*)d_ws;
  if (ws_size < (size_t)(40u << 20)) return;

  short* xb     = (short*)(ws);                        // 8 MiB  [4096][1024] bf16
  short* wqkvT  = (short*)(ws + ((size_t)8u << 20));   // 6 MiB  [3072][1024] bf16
  short* woutT  = (short*)(ws + ((size_t)14u << 20));  // 2 MiB  [1024][1024] bf16
  short* Qb     = (short*)(ws + ((size_t)16u << 20));  // 8 MiB  [B][H][T][D] (prescaled)
  short* Kb     = (short*)(ws + ((size_t)24u << 20));  // 8 MiB
  short* Vb     = (short*)(ws + ((size_t)32u << 20));  // 8 MiB
  short* attn_o = xb;  // xb dead after gemm_qkv

  cast_f32_bf16<<<4096, 256, 0, stream>>>(x, xb);
  transpose_cast<<<dim3(96, 32), dim3(32, 8), 0, stream>>>(w_qkv, wqkvT, 1024, 3072);
  transpose_cast<<<dim3(32, 32), dim3(32, 8), 0, stream>>>(w_out, woutT, 1024, 1024);
  gemm_qkv<<<dim3(32, 24), 256, 0, stream>>>(xb, wqkvT, b_qkv, Qb, Kb, Vb);
  attn_fwd<<<dim3(32, 32), 256, 0, stream>>>(Qb, Kb, Vb, attn_o);
  gemm_out<<<dim3(32, 8), 256, 0, stream>>>(attn_o, woutT, b_out, out);
}

// Round 10
// 119.317 us; speedup vs baseline: 1.3393x; 1.0002x over previous
//
#include <hip/hip_runtime.h>

#define B_ 2
#define T_ 2048
#define C_ 1024
#define H_ 16
#define D_ 64

using bf16x8 = __attribute__((ext_vector_type(8))) short;
using f32x4  = __attribute__((ext_vector_type(4))) float;

static __device__ __forceinline__ short f2bf(float f) {
  unsigned u = __builtin_bit_cast(unsigned, f);
  unsigned r = u + 0x7fffu + ((u >> 16) & 1u);
  return (short)(r >> 16);
}

#define GLD16(gp, lp) __builtin_amdgcn_global_load_lds( \
    (const __attribute__((address_space(1))) void*)(gp), \
    (__attribute__((address_space(3))) void*)(lp), 16, 0, 0)

// ---------------- cast f32 -> bf16 (vectorized) ----------------
__global__ __launch_bounds__(256) void cast_f32_bf16(const float* __restrict__ in,
                                                     short* __restrict__ out) {
  int i = blockIdx.x * blockDim.x + threadIdx.x;
  float4 v = ((const float4*)in)[i];
  short4 o;
  o.x = f2bf(v.x); o.y = f2bf(v.y); o.z = f2bf(v.z); o.w = f2bf(v.w);
  ((short4*)out)[i] = o;
}

// ---------------- transpose + cast: in [R][N] f32 -> out [N][R] bf16 ----------------
__global__ __launch_bounds__(256) void transpose_cast(const float* __restrict__ in,
                                                      short* __restrict__ out,
                                                      int R, int N) {
  __shared__ float tile[32][33];
  int bx = blockIdx.x * 32, by = blockIdx.y * 32;
  int tx = threadIdx.x, ty = threadIdx.y;
  #pragma unroll
  for (int j = 0; j < 32; j += 8)
    tile[ty + j][tx] = in[(size_t)(by + ty + j) * N + bx + tx];
  __syncthreads();
  #pragma unroll
  for (int j = 0; j < 32; j += 8)
    out[(size_t)(bx + ty + j) * R + by + tx] = f2bf(tile[tx][ty + j]);
}

// ---------------- GEMM: 128x128 tile, BK=64, global_load_lds staging ----------------
// Q prescaled by 0.125*log2(e) so attention uses exp2 directly.
__global__ __launch_bounds__(256) void gemm_qkv(const short* __restrict__ A,
                                                const short* __restrict__ Bt,
                                                const float* __restrict__ bias,
                                                short* __restrict__ Qo,
                                                short* __restrict__ Ko,
                                                short* __restrict__ Vo) {
  __shared__ short sA[128 * 64];
  __shared__ short sB[128 * 64];
  const int tid = threadIdx.x;
  const int w = tid >> 6, lane = tid & 63;
  const int wm = w >> 1, wn = w & 1;
  const int g = lane >> 4, r16 = lane & 15;
  const int m0 = blockIdx.x * 128, n0 = blockIdx.y * 128;
  const int krow = lane >> 3, kslot = lane & 7;

  f32x4 acc[4][4] = {};

  for (int k0 = 0; k0 < 1024; k0 += 64) {
    __syncthreads();
    #pragma unroll
    for (int p = 0; p < 4; ++p) {
      int rbase = w * 32 + p * 8;
      int row = rbase + krow;
      GLD16(&A[(size_t)(m0 + row) * 1024 + k0 + ((kslot ^ (row & 7)) * 8)], &sA[rbase * 64]);
      GLD16(&Bt[(size_t)(n0 + row) * 1024 + k0 + ((kslot ^ (row & 7)) * 8)], &sB[rbase * 64]);
    }
    __syncthreads();
    bf16x8 af[4][2], bf[4][2];
    #pragma unroll
    for (int mi = 0; mi < 4; ++mi) {
      int row = wm * 64 + mi * 16 + r16;
      #pragma unroll
      for (int c = 0; c < 2; ++c)
        af[mi][c] = *(const bf16x8*)&sA[row * 64 + (((c * 4 + g) ^ (row & 7)) * 8)];
    }
    #pragma unroll
    for (int ni = 0; ni < 4; ++ni) {
      int row = wn * 64 + ni * 16 + r16;
      #pragma unroll
      for (int c = 0; c < 2; ++c)
        bf[ni][c] = *(const bf16x8*)&sB[row * 64 + (((c * 4 + g) ^ (row & 7)) * 8)];
    }
    __builtin_amdgcn_s_setprio(1);
    #pragma unroll
    for (int mi = 0; mi < 4; ++mi)
      #pragma unroll
      for (int ni = 0; ni < 4; ++ni) {
        acc[mi][ni] = __builtin_amdgcn_mfma_f32_16x16x32_bf16(af[mi][0], bf[ni][0], acc[mi][ni], 0, 0, 0);
        acc[mi][ni] = __builtin_amdgcn_mfma_f32_16x16x32_bf16(af[mi][1], bf[ni][1], acc[mi][ni], 0, 0, 0);
      }
    __builtin_amdgcn_s_setprio(0);
  }

  #pragma unroll
  for (int mi = 0; mi < 4; ++mi) {
    #pragma unroll
    for (int ni = 0; ni < 4; ++ni) {
      int n = n0 + wn * 64 + ni * 16 + r16;
      float bv = bias[n];
      int which = n >> 10;
      int c = n & 1023;
      int hh = c >> 6, d = c & 63;
      short* dst = (which == 0) ? Qo : ((which == 1) ? Ko : Vo);
      float sc = (which == 0) ? 0.18033688f : 1.0f;  // 0.125 * log2(e) folded into Q
      #pragma unroll
      for (int rr = 0; rr < 4; ++rr) {
        int m = m0 + wm * 64 + mi * 16 + g * 4 + rr;
        int b = m >> 11, t = m & 2047;
        dst[(size_t)((b * H_ + hh) * T_ + t) * D_ + d] = f2bf((acc[mi][ni][rr] + bv) * sc);
      }
    }
  }
}

__global__ __launch_bounds__(256) void gemm_out(const short* __restrict__ A,
                                                const short* __restrict__ Bt,
                                                const float* __restrict__ bias,
                                                float* __restrict__ Out) {
  __shared__ short sA[128 * 64];
  __shared__ short sB[128 * 64];
  const int tid = threadIdx.x;
  const int w = tid >> 6, lane = tid & 63;
  const int wm = w >> 1, wn = w & 1;
  const int g = lane >> 4, r16 = lane & 15;
  const int m0 = blockIdx.x * 128, n0 = blockIdx.y * 128;
  const int krow = lane >> 3, kslot = lane & 7;

  f32x4 acc[4][4] = {};

  for (int k0 = 0; k0 < 1024; k0 += 64) {
    __syncthreads();
    #pragma unroll
    for (int p = 0; p < 4; ++p) {
      int rbase = w * 32 + p * 8;
      int row = rbase + krow;
      GLD16(&A[(size_t)(m0 + row) * 1024 + k0 + ((kslot ^ (row & 7)) * 8)], &sA[rbase * 64]);
      GLD16(&Bt[(size_t)(n0 + row) * 1024 + k0 + ((kslot ^ (row & 7)) * 8)], &sB[rbase * 64]);
    }
    __syncthreads();
    bf16x8 af[4][2], bf[4][2];
    #pragma unroll
    for (int mi = 0; mi < 4; ++mi) {
      int row = wm * 64 + mi * 16 + r16;
      #pragma unroll
      for (int c = 0; c < 2; ++c)
        af[mi][c] = *(const bf16x8*)&sA[row * 64 + (((c * 4 + g) ^ (row & 7)) * 8)];
    }
    #pragma unroll
    for (int ni = 0; ni < 4; ++ni) {
      int row = wn * 64 + ni * 16 + r16;
      #pragma unroll
      for (int c = 0; c < 2; ++c)
        bf[ni][c] = *(const bf16x8*)&sB[row * 64 + (((c * 4 + g) ^ (row & 7)) * 8)];
    }
    __builtin_amdgcn_s_setprio(1);
    #pragma unroll
    for (int mi = 0; mi < 4; ++mi)
      #pragma unroll
      for (int ni = 0; ni < 4; ++ni) {
        acc[mi][ni] = __builtin_amdgcn_mfma_f32_16x16x32_bf16(af[mi][0], bf[ni][0], acc[mi][ni], 0, 0, 0);
        acc[mi][ni] = __builtin_amdgcn_mfma_f32_16x16x32_bf16(af[mi][1], bf[ni][1], acc[mi][ni], 0, 0, 0);
      }
    __builtin_amdgcn_s_setprio(0);
  }

  #pragma unroll
  for (int mi = 0; mi < 4; ++mi) {
    #pragma unroll
    for (int ni = 0; ni < 4; ++ni) {
      int n = n0 + wn * 64 + ni * 16 + r16;
      float bv = bias[n];
      #pragma unroll
      for (int rr = 0; rr < 4; ++rr) {
        int m = m0 + wm * 64 + mi * 16 + g * 4 + rr;
        Out[(size_t)m * 1024 + n] = acc[mi][ni][rr] + bv;
      }
    }
  }
}

// ---------------- flash attention: deferred-PV pipeline + tree reductions ----------------
// grid (bh=32, 32); qi = 31 - blockIdx.y (LPT). 4 waves x 16 q-rows, KVBLK=64.
// PV(kt-1) runs at the TOP of iteration kt (overlaps staging issue, off the softmax
// critical path); vT triple-buffered (%3) so write (kt+1) and read (kt-1) never clash.
// Softmax: swapped mfma(K,Q), per-lane partial l, defer-max, tree-structured reductions.
__global__ __launch_bounds__(256, 4) void attn_fwd(const short* __restrict__ Q,
                                                   const short* __restrict__ K,
                                                   const short* __restrict__ V,
                                                   short* __restrict__ O) {
  __shared__ short sK[2][64 * 64];   // [key][d], chunk c holds d-chunk c^(key&7)
  __shared__ short vT[3][64 * 64];   // [d][slot], slot = pi(key); chunk c' holds c'^(d&7)

  const int tid = threadIdx.x;
  const int w = tid >> 6, lane = tid & 63;
  const int g = lane >> 4, r16 = lane & 15;
  const int bh = blockIdx.x;
  const int b = bh >> 4, hh = bh & 15;
  const int qi = 31 - (int)blockIdx.y;  // LPT: heavy first
  const int q0 = qi * 64;

  const short* Qh = Q + (size_t)bh * T_ * D_;
  const short* Kh = K + (size_t)bh * T_ * D_;
  const short* Vh = V + (size_t)bh * T_ * D_;

  const int krow_in_wave = lane >> 3;
  const int kslot = lane & 7;
  // V slot permutation: slot = 32a + 8c + 4b + 2d + e for key = 32a+16b+4c+2d+e
  const int kp = tid & 31;
  const int vd0 = (tid >> 5) * 8;
  const int vchunk = (kp >> 4) * 4 + ((kp & 7) >> 1);
  const int velem  = ((kp >> 3) & 1) * 4 + 2 * (kp & 1);

  const int qrow_a = q0 + w * 16 + r16;
  bf16x8 qf[2];
  qf[0] = *(const bf16x8*)&Qh[(size_t)qrow_a * 64 + g * 8];
  qf[1] = *(const bf16x8*)&Qh[(size_t)qrow_a * 64 + 32 + g * 8];

  f32x4 o[4] = {};
  float m_ = -1e30f, l_ = 0.f;   // l_ is a PER-LANE partial (scale 2^-m_)
  bf16x8 pa[2];                  // packed P of the PREVIOUS tile (lives across barrier)

  const int nkt = qi + 1;

  // ---- prologue: stage K(0) -> sK[0], V(0) -> vT[0] ----
  #pragma unroll
  for (int p = 0; p < 2; ++p) {
    int row = w * 16 + p * 8 + krow_in_wave;
    GLD16(&Kh[(size_t)row * 64 + ((kslot ^ (row & 7)) * 8)], &sK[0][(w * 16 + p * 8) * 64]);
  }
  {
    int4 v0 = *(const int4*)&Vh[(size_t)(2 * kp) * 64 + vd0];
    int4 v1 = *(const int4*)&Vh[(size_t)(2 * kp + 1) * 64 + vd0];
    const short* a0 = (const short*)&v0;
    const short* a1 = (const short*)&v1;
    #pragma unroll
    for (int j = 0; j < 8; ++j) {
      int d = vd0 + j;  // d&7 == j
      int val = ((int)(unsigned short)a0[j]) | (((int)(unsigned short)a1[j]) << 16);
      *(int*)&vT[0][d * 64 + ((vchunk ^ j) * 8) + velem] = val;
    }
  }
  __syncthreads();

  for (int kt = 0; kt < nkt; ++kt) {
    const int cur = kt & 1, nxt = cur ^ 1;
    const int k0 = kt * 64;
    const bool pf = (kt + 1 < nkt);

    // ---- issue next-tile staging early (T14) ----
    int4 vn0, vn1;
    if (pf) {
      const int k1 = k0 + 64;
      #pragma unroll
      for (int p = 0; p < 2; ++p) {
        int row = w * 16 + p * 8 + krow_in_wave;
        GLD16(&Kh[(size_t)(k1 + row) * 64 + ((kslot ^ (row & 7)) * 8)],
              &sK[nxt][(w * 16 + p * 8) * 64]);
      }
      vn0 = *(const int4*)&Vh[(size_t)(k1 + 2 * kp) * 64 + vd0];
      vn1 = *(const int4*)&Vh[(size_t)(k1 + 2 * kp + 1) * 64 + vd0];
    }

    // ---- deferred PV(kt-1): overlaps the staging issue, off the softmax path ----
    if (kt > 0) {
      const short* vp = vT[(kt - 1) % 3];
      __builtin_amdgcn_s_setprio(1);
      #pragma unroll
      for (int nt = 0; nt < 4; ++nt) {
        const int d = nt * 16 + r16;
        bf16x8 vb0 = *(const bf16x8*)&vp[d * 64 + ((g ^ (d & 7)) * 8)];
        bf16x8 vb1 = *(const bf16x8*)&vp[d * 64 + (((4 + g) ^ (d & 7)) * 8)];
        o[nt] = __builtin_amdgcn_mfma_f32_16x16x32_bf16(pa[0], vb0, o[nt], 0, 0, 0);
        o[nt] = __builtin_amdgcn_mfma_f32_16x16x32_bf16(pa[1], vb1, o[nt], 0, 0, 0);
      }
      __builtin_amdgcn_s_setprio(0);
    }

    // ---- S^T = K Q^T : lane holds S[key = nt*16+4g+rr][q = r16] ----
    f32x4 s[4] = {};
    __builtin_amdgcn_s_setprio(1);
    #pragma unroll
    for (int nt = 0; nt < 4; ++nt) {
      const int row = nt * 16 + r16;
      const int sw8 = r16 & 7;
      bf16x8 kf0 = *(const bf16x8*)&sK[cur][row * 64 + ((g ^ sw8) * 8)];
      bf16x8 kf1 = *(const bf16x8*)&sK[cur][row * 64 + (((4 + g) ^ sw8) * 8)];
      s[nt] = __builtin_amdgcn_mfma_f32_16x16x32_bf16(kf0, qf[0], s[nt], 0, 0, 0);
      s[nt] = __builtin_amdgcn_mfma_f32_16x16x32_bf16(kf1, qf[1], s[nt], 0, 0, 0);
    }
    __builtin_amdgcn_s_setprio(0);

    // ---- online softmax (log2 domain; Q prescaled); tree reductions ----
    if (kt == nkt - 1) {  // diagonal tile
      const int qrow = w * 16 + r16;
      #pragma unroll
      for (int nt = 0; nt < 4; ++nt)
        #pragma unroll
        for (int rr = 0; rr < 4; ++rr)
          if (nt * 16 + 4 * g + rr > qrow) s[nt][rr] = -1e30f;
    }
    // pairwise-tree max (4 dependency levels)
    float x0 = fmaxf(s[0][0], s[0][1]), x1 = fmaxf(s[0][2], s[0][3]);
    float x2 = fmaxf(s[1][0], s[1][1]), x3 = fmaxf(s[1][2], s[1][3]);
    float x4 = fmaxf(s[2][0], s[2][1]), x5 = fmaxf(s[2][2], s[2][3]);
    float x6 = fmaxf(s[3][0], s[3][1]), x7 = fmaxf(s[3][2], s[3][3]);
    x0 = fmaxf(x0, x1); x2 = fmaxf(x2, x3); x4 = fmaxf(x4, x5); x6 = fmaxf(x6, x7);
    x0 = fmaxf(x0, x2); x4 = fmaxf(x4, x6);
    float pmax = fmaxf(x0, x4);
    // defer-max gate on PER-LANE max (no reduce needed to check)
    if (!__all(pmax - m_ <= 8.0f)) {
      float rmax = fmaxf(pmax, __shfl_xor(pmax, 16));
      rmax = fmaxf(rmax, __shfl_xor(rmax, 32));
      float mn = fmaxf(m_, rmax);
      float al = __builtin_amdgcn_exp2f(m_ - mn);
      m_ = mn;
      l_ *= al;
      float av[4];
      #pragma unroll
      for (int rr = 0; rr < 4; ++rr) av[rr] = __shfl(al, 4 * g + rr, 16);
      #pragma unroll
      for (int nt = 0; nt < 4; ++nt)
        #pragma unroll
        for (int rr = 0; rr < 4; ++rr) o[nt][rr] *= av[rr];
    }
    #pragma unroll
    for (int nt = 0; nt < 4; ++nt)
      #pragma unroll
      for (int rr = 0; rr < 4; ++rr)
        s[nt][rr] = __builtin_amdgcn_exp2f(s[nt][rr] - m_);
    // pairwise-tree sum
    float y0 = s[0][0] + s[0][1], y1 = s[0][2] + s[0][3];
    float y2 = s[1][0] + s[1][1], y3 = s[1][2] + s[1][3];
    float y4 = s[2][0] + s[2][1], y5 = s[2][2] + s[2][3];
    float y6 = s[3][0] + s[3][1], y7 = s[3][2] + s[3][3];
    y0 += y1; y2 += y3; y4 += y5; y6 += y7;
    y0 += y2; y4 += y6;
    l_ += y0 + y4;  // per-lane partial; cross-lane reduce deferred to epilogue
    int pk[8];
    #pragma unroll
    for (int nt = 0; nt < 4; ++nt)
      #pragma unroll
      for (int h = 0; h < 2; ++h)
        asm("v_cvt_pk_bf16_f32 %0, %1, %2"
            : "=v"(pk[nt * 2 + h])
            : "v"(s[nt][2 * h]), "v"(s[nt][2 * h + 1]));
    {
      int4 t0; t0.x = pk[0]; t0.y = pk[1]; t0.z = pk[2]; t0.w = pk[3];
      int4 t1; t1.x = pk[4]; t1.y = pk[5]; t1.z = pk[6]; t1.w = pk[7];
      pa[0] = __builtin_bit_cast(bf16x8, t0);
      pa[1] = __builtin_bit_cast(bf16x8, t1);
    }

    // ---- late stage-write of V(kt+1) into vT[(kt+1)%3] ----
    if (pf) {
      short* vpn = vT[(kt + 1) % 3];
      const short* a0 = (const short*)&vn0;
      const short* a1 = (const short*)&vn1;
      #pragma unroll
      for (int j = 0; j < 8; ++j) {
        int d = vd0 + j;
        int val = ((int)(unsigned short)a0[j]) | (((int)(unsigned short)a1[j]) << 16);
        *(int*)&vpn[d * 64 + ((vchunk ^ j) * 8) + velem] = val;
      }
    }
    __syncthreads();
  }

  // ---- drain: final PV(nkt-1) ----
  {
    const short* vp = vT[(nkt - 1) % 3];
    #pragma unroll
    for (int nt = 0; nt < 4; ++nt) {
      const int d = nt * 16 + r16;
      bf16x8 vb0 = *(const bf16x8*)&vp[d * 64 + ((g ^ (d & 7)) * 8)];
      bf16x8 vb1 = *(const bf16x8*)&vp[d * 64 + (((4 + g) ^ (d & 7)) * 8)];
      o[nt] = __builtin_amdgcn_mfma_f32_16x16x32_bf16(pa[0], vb0, o[nt], 0, 0, 0);
      o[nt] = __builtin_amdgcn_mfma_f32_16x16x32_bf16(pa[1], vb1, o[nt], 0, 0, 0);
    }
  }

  // ---- epilogue: reduce per-lane l partials once, then O /= l ----
  float lt = l_ + __shfl_xor(l_, 16);
  lt += __shfl_xor(lt, 32);
  float lv[4];
  #pragma unroll
  for (int rr = 0; rr < 4; ++rr) lv[rr] = __shfl(lt, 4 * g + rr, 16);
  #pragma unroll
  for (int nt = 0; nt < 4; ++nt) {
    int d = nt * 16 + r16;
    #pragma unroll
    for (int rr = 0; rr < 4; ++rr) {
      int t = q0 + w * 16 + 4 * g + rr;
      O[(size_t)(b * T_ + t) * C_ + hh * 64 + d] = f2bf(o[nt][rr] / lv[rr]);
    }
  }
}

extern "C" void kernel_launch(void* const* d_in, const int* in_sizes, int n_in,
                              void* d_out, int out_size, void* d_ws, size_t ws_size,
                              hipStream_t stream) {
  const float* x     = (const float*)d_in[0];
  const float* w_qkv = (const float*)d_in[1];
  const float* b_qkv = (const float*)d_in[2];
  const float* w_out = (const float*)d_in[3];
  const float* b_out = (const float*)d_in[4];
  float* out = (float*)d_out;

  char* ws = (char*)d_ws;
  if (ws_size < (size_t)(40u << 20)) return;

  short* xb     = (short*)(ws);                        // 8 MiB  [4096][1024] bf16
  short* wqkvT  = (short*)(ws + ((size_t)8u << 20));   // 6 MiB  [3072][1024] bf16
  short* woutT  = (short*)(ws + ((size_t)14u << 20));  // 2 MiB  [1024][1024] bf16
  short* Qb     = (short*)(ws + ((size_t)16u << 20));  // 8 MiB  [B][H][T][D] (prescaled)
  short* Kb     = (short*)(ws + ((size_t)24u << 20));  // 8 MiB
  short* Vb     = (short*)(ws + ((size_t)32u << 20));  // 8 MiB
  short* attn_o = xb;  // xb dead after gemm_qkv

  cast_f32_bf16<<<4096, 256, 0, stream>>>(x, xb);
  transpose_cast<<<dim3(96, 32), dim3(32, 8), 0, stream>>>(w_qkv, wqkvT, 1024, 3072);
  transpose_cast<<<dim3(32, 32), dim3(32, 8), 0, stream>>>(w_out, woutT, 1024, 1024);
  gemm_qkv<<<dim3(32, 24), 256, 0, stream>>>(xb, wqkvT, b_qkv, Qb, Kb, Vb);
  attn_fwd<<<dim3(32, 32), 256, 0, stream>>>(Qb, Kb, Vb, attn_o);
  gemm_out<<<dim3(32, 8), 256, 0, stream>>>(attn_o, woutT, b_out, out);
}